// Round 7
// baseline (718.403 us; speedup 1.0000x reference)
//
#include <hip/hip_runtime.h>
#include <hip/hip_fp16.h>

#define NSEQ 8192
#define DIM  512
#define SPITCH 8256            // f32 elems per S row (NSEQ + 64)
#define SROWB  33024           // bytes per S row
#define VPITCH 8256            // f16 elems per row-major XhT (fallback path)

typedef _Float16 f16;
typedef _Float16 f16x8 __attribute__((ext_vector_type(8)));
typedef _Float16 f16x4 __attribute__((ext_vector_type(4)));
typedef float    f32x4 __attribute__((ext_vector_type(4)));

// Fragment-tiled layout: matrix (R rows x C k-cols) stored as (R/16)x(C/32)
// frags of 512 f16. In-frag: lane l = ((k>>3)&3)*16 + (r&15) holds elems
// k = (l>>4)*8 + e.  f16 offset:
//   ((r>>4)*(C>>5) + (k>>5))*512 + (((k>>3)&3)*16 + (r&15))*8 + (k&7)
// Reader: frag(rt,kt) at lane*8 -> one coalesced 1KB wave load.

// ---------------------------------------------------------------------------
// X (fp32) -> Xh + Xl (f16 hi/lo split), row-major (k_proj2 staging input).
// ---------------------------------------------------------------------------
__global__ __launch_bounds__(256) void k_splitx(const float* __restrict__ X,
                                                f16* __restrict__ Xh,
                                                f16* __restrict__ Xl)
{
  const size_t idx = (size_t)blockIdx.x * 256 + threadIdx.x;
  f32x4 v = *(const f32x4*)(X + idx * 4);
  f16x4 h, l;
#pragma unroll
  for (int i = 0; i < 4; ++i) {
    h[i] = (f16)v[i];
    l[i] = (f16)(v[i] - (float)h[i]);
  }
  *(f16x4*)(Xh + idx * 4) = h;
  *(f16x4*)(Xl + idx * 4) = l;
}

// ---------------------------------------------------------------------------
// W (512x512 fp32) -> Wt^T split: Wth/Wtl[c][k] = split(W[k][c]). Row-major.
// ---------------------------------------------------------------------------
__global__ __launch_bounds__(256) void k_splitwt(const float* __restrict__ W,
                                                 f16* __restrict__ Th,
                                                 f16* __restrict__ Tl)
{
  __shared__ float T[64][65];
  const int tid = threadIdx.x;
  const int k0 = blockIdx.x * 64;
  const int c0 = blockIdx.y * 64;
#pragma unroll
  for (int e = 0; e < 16; ++e) {
    int idx = tid + e * 256;
    T[idx >> 6][idx & 63] = W[(size_t)(k0 + (idx >> 6)) * DIM + c0 + (idx & 63)];
  }
  __syncthreads();
#pragma unroll
  for (int e = 0; e < 16; ++e) {
    int idx = tid + e * 256;
    int cc = idx >> 6, kk = idx & 63;
    float v = T[kk][cc];
    f16 h = (f16)v;
    Th[(size_t)(c0 + cc) * DIM + k0 + kk] = h;
    Tl[(size_t)(c0 + cc) * DIM + k0 + kk] = (f16)(v - (float)h);
  }
}

// ---------------------------------------------------------------------------
// X -> XhTf: frag-tiled V^T (rows = d (512), k-cols = j (8192), C>>5 = 256).
// ---------------------------------------------------------------------------
__global__ __launch_bounds__(256) void k_xt2(const float* __restrict__ X,
                                             f16* __restrict__ XhTf)
{
  __shared__ float T[64][65];
  const int tid = threadIdx.x;
  const int j0 = blockIdx.x * 64;
  const int d0 = blockIdx.y * 64;
#pragma unroll
  for (int e = 0; e < 16; ++e) {
    int idx = tid + e * 256;
    T[idx >> 6][idx & 63] = X[(size_t)(j0 + (idx >> 6)) * DIM + d0 + (idx & 63)];
  }
  __syncthreads();
#pragma unroll
  for (int e = 0; e < 16; ++e) {
    int idx = tid + e * 256;
    int dd = idx >> 6, jj = idx & 63;
    int d = d0 + dd, j = j0 + jj;
    size_t off = ((size_t)(d >> 4) * 256 + (j >> 5)) * 512
               + (((j >> 3) & 3) * 16 + (d & 15)) * 8 + (j & 7);
    XhTf[off] = (f16)T[jj][dd];
  }
}

// ---------------------------------------------------------------------------
// Fallback: X -> XhT row-major [d][j], pitch VPITCH.
// ---------------------------------------------------------------------------
__global__ __launch_bounds__(256) void k_xt(const float* __restrict__ X,
                                            f16* __restrict__ XhT)
{
  __shared__ float T[64][65];
  const int tid = threadIdx.x;
  const int j0 = blockIdx.x * 64;
  const int d0 = blockIdx.y * 64;
#pragma unroll
  for (int e = 0; e < 16; ++e) {
    int idx = tid + e * 256;
    T[idx >> 6][idx & 63] = X[(size_t)(j0 + (idx >> 6)) * DIM + d0 + (idx & 63)];
  }
  __syncthreads();
#pragma unroll
  for (int e = 0; e < 16; ++e) {
    int idx = tid + e * 256;
    int dd = idx >> 6, jj = idx & 63;
    XhT[(size_t)(d0 + dd) * VPITCH + j0 + jj] = (f16)T[jj][dd];
  }
}

// ---------------------------------------------------------------------------
// Projection: C = X W (M=8192,N=512,K=512), split-f16 3-term MFMA, LDS-staged
// (k_qkt-style). Epilogue writes Oh/Ol FRAG-TILED (rows=q, k-cols=d, C>>5=16).
// ---------------------------------------------------------------------------
__global__ __launch_bounds__(256) void k_proj2(
    const f16* __restrict__ Xh, const f16* __restrict__ Xl,
    const f16* __restrict__ Wth, const f16* __restrict__ Wtl,
    f16* __restrict__ Oh, f16* __restrict__ Ol, float scale)
{
  __shared__ char sm[4 * 8192];
  const int tid  = threadIdx.x;
  const int lane = tid & 63;
  const int w    = tid >> 6;
  const int wm   = (w >> 1) * 64;
  const int wn   = (w & 1) * 64;
  const int row0g = blockIdx.x * 128;
  const int col0g = blockIdx.y * 128;

  const int r1 = tid >> 2;
  const int o1 = (tid & 3) * 8;
  const int sw1 = (r1 * 64 + (tid & 3) * 16) ^ ((r1 & 7) << 4);
  const int sw2 = ((r1 + 64) * 64 + (tid & 3) * 16) ^ (((r1 + 64) & 7) << 4);
  const f16* pAh = Xh  + (size_t)(row0g + r1) * DIM + o1;
  const f16* pAl = Xl  + (size_t)(row0g + r1) * DIM + o1;
  const f16* pBh = Wth + (size_t)(col0g + r1) * DIM + o1;
  const f16* pBl = Wtl + (size_t)(col0g + r1) * DIM + o1;
  const int R64 = 64 * DIM;

  const int frow = lane & 15;
  const int lhi  = lane >> 4;
  const int fkb  = lhi * 16;

  f32x4 acc[4][4] = {};

  for (int step = 0; step < 16; ++step) {
    const int d0 = step * 32;
    uint4 v0 = *(const uint4*)(pAh + d0);
    uint4 v1 = *(const uint4*)(pAh + R64 + d0);
    uint4 v2 = *(const uint4*)(pAl + d0);
    uint4 v3 = *(const uint4*)(pAl + R64 + d0);
    uint4 v4 = *(const uint4*)(pBh + d0);
    uint4 v5 = *(const uint4*)(pBh + R64 + d0);
    uint4 v6 = *(const uint4*)(pBl + d0);
    uint4 v7 = *(const uint4*)(pBl + R64 + d0);
    __syncthreads();
    *(uint4*)(sm +     0 + sw1) = v0;
    *(uint4*)(sm +     0 + sw2) = v1;
    *(uint4*)(sm +  8192 + sw1) = v2;
    *(uint4*)(sm +  8192 + sw2) = v3;
    *(uint4*)(sm + 16384 + sw1) = v4;
    *(uint4*)(sm + 16384 + sw2) = v5;
    *(uint4*)(sm + 24576 + sw1) = v6;
    *(uint4*)(sm + 24576 + sw2) = v7;
    __syncthreads();
    f16x8 aH[4], aL[4], bH[4], bL[4];
#pragma unroll
    for (int m = 0; m < 4; ++m) {
      int ra = wm + m * 16 + frow;
      int rb = wn + m * 16 + frow;
      int sa = (ra * 64 + fkb) ^ ((ra & 7) << 4);
      int sb = (rb * 64 + fkb) ^ ((rb & 7) << 4);
      aH[m] = *(const f16x8*)(sm +     0 + sa);
      aL[m] = *(const f16x8*)(sm +  8192 + sa);
      bH[m] = *(const f16x8*)(sm + 16384 + sb);
      bL[m] = *(const f16x8*)(sm + 24576 + sb);
    }
#pragma unroll
    for (int m = 0; m < 4; ++m)
#pragma unroll
      for (int n = 0; n < 4; ++n) {
        acc[m][n] = __builtin_amdgcn_mfma_f32_16x16x32_f16(aH[m], bH[n], acc[m][n], 0, 0, 0);
        acc[m][n] = __builtin_amdgcn_mfma_f32_16x16x32_f16(aH[m], bL[n], acc[m][n], 0, 0, 0);
        acc[m][n] = __builtin_amdgcn_mfma_f32_16x16x32_f16(aL[m], bH[n], acc[m][n], 0, 0, 0);
      }
  }

  const int row0 = row0g + wm;
  const int col0 = col0g + wn;
#pragma unroll
  for (int m = 0; m < 4; ++m)
#pragma unroll
    for (int n = 0; n < 4; ++n) {
      int dd = col0 + n * 16 + frow;
#pragma unroll
      for (int r = 0; r < 4; ++r) {
        int qq = row0 + m * 16 + lhi * 4 + r;
        float c = acc[m][n][r] * scale;
        f16 h = (f16)c;
        size_t off = ((size_t)(qq >> 4) * 16 + (dd >> 5)) * 512
                   + (((dd >> 3) & 3) * 16 + (qq & 15)) * 8 + (dd & 7);
        Oh[off] = h;
        Ol[off] = (f16)(c - (float)h);
      }
    }
}

// ---------------------------------------------------------------------------
// S = Q K^T, frag-direct (no LDS): all operands frag-tiled (k-cols = d, 16
// frags per 16-row group). 128x128 tile, 4 waves, 3-term split, BK=32.
// ---------------------------------------------------------------------------
__global__ __launch_bounds__(256, 2) void k_qkt2(
    const f16* __restrict__ Qh, const f16* __restrict__ Ql,
    const f16* __restrict__ Kh, const f16* __restrict__ Kl,
    float* __restrict__ S, int q0)
{
  const int tid  = threadIdx.x;
  const int lane = tid & 63;
  const int w    = tid >> 6;
  const int wm   = (w >> 1) * 64;
  const int wn   = (w & 1) * 64;
  const int qrow0 = q0 + blockIdx.x * 128;
  const int krow0 = blockIdx.y * 128;

  const size_t qfr = (size_t)((qrow0 + wm) >> 4) * 8192 + lane * 8;
  const size_t kfr = (size_t)((krow0 + wn) >> 4) * 8192 + lane * 8;
  const f16* pQh = Qh + qfr;
  const f16* pQl = Ql + qfr;
  const f16* pKh = Kh + kfr;
  const f16* pKl = Kl + kfr;

  f32x4 acc[4][4] = {};
#pragma unroll 2
  for (int dt = 0; dt < 16; ++dt) {
    f16x8 aH[4], aL[4], bH[4], bL[4];
#pragma unroll
    for (int m = 0; m < 4; ++m) {
      aH[m] = *(const f16x8*)(pQh + m * 8192 + dt * 512);
      aL[m] = *(const f16x8*)(pQl + m * 8192 + dt * 512);
      bH[m] = *(const f16x8*)(pKh + m * 8192 + dt * 512);
      bL[m] = *(const f16x8*)(pKl + m * 8192 + dt * 512);
    }
#pragma unroll
    for (int m = 0; m < 4; ++m)
#pragma unroll
      for (int n = 0; n < 4; ++n) {
        acc[m][n] = __builtin_amdgcn_mfma_f32_16x16x32_f16(aH[m], bH[n], acc[m][n], 0, 0, 0);
        acc[m][n] = __builtin_amdgcn_mfma_f32_16x16x32_f16(aH[m], bL[n], acc[m][n], 0, 0, 0);
        acc[m][n] = __builtin_amdgcn_mfma_f32_16x16x32_f16(aL[m], bH[n], acc[m][n], 0, 0, 0);
      }
  }

  const int srow0 = blockIdx.x * 128 + wm;   // chunk-local S row
  const int scol0 = krow0 + wn;
  const int lhi = lane >> 4;
#pragma unroll
  for (int m = 0; m < 4; ++m)
#pragma unroll
    for (int n = 0; n < 4; ++n) {
      int row = srow0 + m * 16 + lhi * 4;
      int col = scol0 + n * 16 + (lane & 15);
#pragma unroll
      for (int r = 0; r < 4; ++r)
        S[(size_t)(row + r) * SPITCH + col] = acc[m][n][r];
    }
}

// ---------------------------------------------------------------------------
// Softmax writing FRAG-TILED P (rows=q, k-cols=j, 256 frags/row-group).
// ---------------------------------------------------------------------------
__global__ __launch_bounds__(256) void k_softmax2(
    const float* __restrict__ S, f16* __restrict__ Pf,
    float* __restrict__ Lsum, int q0)
{
  __shared__ float red[4], red2[4];
  const int tid = threadIdx.x;
  const int r = blockIdx.x;
  const int qg = q0 + r;
  const float* srow = S + (size_t)r * SPITCH;
  f32x4 v[8];
#pragma unroll
  for (int e = 0; e < 8; ++e)
    v[e] = *(const f32x4*)(srow + (size_t)(tid + e * 256) * 4);
  float m = -3.0e38f;
#pragma unroll
  for (int e = 0; e < 8; ++e)
#pragma unroll
    for (int i = 0; i < 4; ++i) m = fmaxf(m, v[e][i]);
#pragma unroll
  for (int off = 32; off; off >>= 1) m = fmaxf(m, __shfl_xor(m, off));
  if ((tid & 63) == 0) red[tid >> 6] = m;
  __syncthreads();
  m = fmaxf(fmaxf(red[0], red[1]), fmaxf(red[2], red[3]));
  float sum = 0.f;
#pragma unroll
  for (int e = 0; e < 8; ++e)
#pragma unroll
    for (int i = 0; i < 4; ++i) {
      float p = __expf(v[e][i] - m);
      v[e][i] = p;
      sum += p;
    }
#pragma unroll
  for (int off = 32; off; off >>= 1) sum += __shfl_xor(sum, off);
  if ((tid & 63) == 0) red2[tid >> 6] = sum;
  __syncthreads();
  sum = red2[0] + red2[1] + red2[2] + red2[3];
  if (tid == 0) Lsum[qg] = sum;

  const size_t rowbase = (size_t)(qg >> 4) * 131072;   // 256 frags * 512
  const int qm8 = (qg & 15) * 8;
#pragma unroll
  for (int e = 0; e < 8; ++e) {
    f16x4 p;
#pragma unroll
    for (int i = 0; i < 4; ++i) p[i] = (f16)v[e][i];
    int jj = (tid + e * 256) * 4;
    size_t off = rowbase + (size_t)(jj >> 5) * 512
               + (((jj >> 3) & 3) * 16) * 8 + qm8 + (jj & 7);
    *(f16x4*)(Pf + off) = p;
  }
}

// ---------------------------------------------------------------------------
// Fallback softmax: row-major P (pitch SPITCH f16).
// ---------------------------------------------------------------------------
__global__ __launch_bounds__(256) void k_softmax_row(
    const float* __restrict__ S, f16* __restrict__ P,
    float* __restrict__ Lsum, int q0)
{
  __shared__ float red[4], red2[4];
  const int tid = threadIdx.x;
  const int r = blockIdx.x;
  const float* srow = S + (size_t)r * SPITCH;
  f32x4 v[8];
#pragma unroll
  for (int e = 0; e < 8; ++e)
    v[e] = *(const f32x4*)(srow + (size_t)(tid + e * 256) * 4);
  float m = -3.0e38f;
#pragma unroll
  for (int e = 0; e < 8; ++e)
#pragma unroll
    for (int i = 0; i < 4; ++i) m = fmaxf(m, v[e][i]);
#pragma unroll
  for (int off = 32; off; off >>= 1) m = fmaxf(m, __shfl_xor(m, off));
  if ((tid & 63) == 0) red[tid >> 6] = m;
  __syncthreads();
  m = fmaxf(fmaxf(red[0], red[1]), fmaxf(red[2], red[3]));
  float sum = 0.f;
#pragma unroll
  for (int e = 0; e < 8; ++e)
#pragma unroll
    for (int i = 0; i < 4; ++i) {
      float p = __expf(v[e][i] - m);
      v[e][i] = p;
      sum += p;
    }
#pragma unroll
  for (int off = 32; off; off >>= 1) sum += __shfl_xor(sum, off);
  if ((tid & 63) == 0) red2[tid >> 6] = sum;
  __syncthreads();
  sum = red2[0] + red2[1] + red2[2] + red2[3];
  if (tid == 0) Lsum[q0 + r] = sum;
  f16* prow = P + (size_t)(q0 + r) * SPITCH;
#pragma unroll
  for (int e = 0; e < 8; ++e) {
    f16x4 p;
#pragma unroll
    for (int i = 0; i < 4; ++i) p[i] = (f16)v[e][i];
    *(f16x4*)(prow + (size_t)(tid + e * 256) * 4) = p;
  }
}

// ---------------------------------------------------------------------------
// PV frag-direct: Opart^T = XhTf * Pf^T. Block = 4 waves = 32q x 512d.
// 1-D grid 256*Z, xcd (bid&7) selects z-slice -> per-XCD L2-resident A.
// All operand loads are coalesced 1KB frag loads.
// ---------------------------------------------------------------------------
__global__ __launch_bounds__(256, 4) void k_pv2f(
    const f16* __restrict__ XhTf, const f16* __restrict__ Pf,
    char* __restrict__ obase, size_t qstride, size_t zstride,
    int jrange, int Z)
{
  const int tid  = threadIdx.x;
  const int lane = tid & 63;
  const int w    = tid >> 6;
  const int frow = lane & 15;
  const int lhi  = lane >> 4;

  const int bid = blockIdx.x;
  const int xcd = bid & 7;
  const int g   = bid >> 3;
  const int pz  = 8 / Z;                       // Z in {1,2,4}
  const int z   = xcd / pz;
  const int q0  = (g * pz + (xcd % pz)) * 32;
  const int fr0 = (z * jrange) >> 5;           // first frag col

  const f16* pa  = XhTf + (size_t)(w * 8) * 131072 + (size_t)fr0 * 512 + lane * 8;
  const f16* pb0 = Pf + (size_t)(q0 >> 4) * 131072 + (size_t)fr0 * 512 + lane * 8;
  const f16* pb1 = pb0 + 131072;

  f32x4 acc[8][2] = {};
  const int nsteps = jrange / 32;
#pragma unroll 2
  for (int s = 0; s < nsteps; ++s) {
    f16x8 b0 = *(const f16x8*)(pb0 + s * 512);
    f16x8 b1 = *(const f16x8*)(pb1 + s * 512);
#pragma unroll
    for (int m2 = 0; m2 < 8; ++m2) {
      f16x8 a = *(const f16x8*)(pa + (size_t)m2 * 131072 + s * 512);
      acc[m2][0] = __builtin_amdgcn_mfma_f32_16x16x32_f16(a, b0, acc[m2][0], 0, 0, 0);
      acc[m2][1] = __builtin_amdgcn_mfma_f32_16x16x32_f16(a, b1, acc[m2][1], 0, 0, 0);
    }
  }

#pragma unroll
  for (int m2 = 0; m2 < 8; ++m2)
#pragma unroll
    for (int n2 = 0; n2 < 2; ++n2) {
      const int qg = q0 + n2 * 16 + frow;
      char* p = obase + (size_t)qg * qstride + (size_t)z * zstride
                      + (size_t)(w * 128 + m2 * 16 + lhi * 4) * 4;
      *(f32x4*)p = acc[m2][n2];
    }
}

// ---------------------------------------------------------------------------
// Fallback PV: row-major XhT (VPITCH) + row-major P (SPITCH), scattered frags.
// ---------------------------------------------------------------------------
__global__ __launch_bounds__(256, 4) void k_pv2_row(
    const f16* __restrict__ XhT, const f16* __restrict__ P,
    char* __restrict__ obase, size_t qstride, size_t zstride,
    int jrange, int Z)
{
  const int tid  = threadIdx.x;
  const int lane = tid & 63;
  const int w    = tid >> 6;
  const int frow = lane & 15;
  const int lhi  = lane >> 4;

  const int bid = blockIdx.x;
  const int xcd = bid & 7;
  const int g   = bid >> 3;
  const int pz  = 8 / Z;
  const int z   = xcd / pz;
  const int q0  = (g * pz + (xcd % pz)) * 32;
  const int jbase = z * jrange;

  const f16* pa  = XhT + (size_t)(w * 128 + frow) * VPITCH + jbase + lhi * 8;
  const f16* pb0 = P + (size_t)(q0 + frow) * SPITCH + jbase + lhi * 8;
  const f16* pb1 = pb0 + (size_t)16 * SPITCH;

  f32x4 acc[8][2] = {};
  const int nsteps = jrange / 32;
  for (int s = 0; s < nsteps; ++s) {
    const int j = s * 32;
    f16x8 b0 = *(const f16x8*)(pb0 + j);
    f16x8 b1 = *(const f16x8*)(pb1 + j);
#pragma unroll
    for (int m2 = 0; m2 < 8; ++m2) {
      f16x8 a = *(const f16x8*)(pa + (size_t)(m2 * 16) * VPITCH + j);
      acc[m2][0] = __builtin_amdgcn_mfma_f32_16x16x32_f16(a, b0, acc[m2][0], 0, 0, 0);
      acc[m2][1] = __builtin_amdgcn_mfma_f32_16x16x32_f16(a, b1, acc[m2][1], 0, 0, 0);
    }
  }

#pragma unroll
  for (int m2 = 0; m2 < 8; ++m2)
#pragma unroll
    for (int n2 = 0; n2 < 2; ++n2) {
      const int qg = q0 + n2 * 16 + frow;
      char* p = obase + (size_t)qg * qstride + (size_t)z * zstride
                      + (size_t)(w * 128 + m2 * 16 + lhi * 4) * 4;
      *(f32x4*)p = acc[m2][n2];
    }
}

// ---------------------------------------------------------------------------
// Out[q][d] = (sum_z Opart[z][q][d]) / Lsum[q]. In-place when obase==Out.
// ---------------------------------------------------------------------------
__global__ __launch_bounds__(256) void k_reduce(
    const char* __restrict__ obase, size_t qstride, size_t zstride, int Z,
    const float* __restrict__ Lsum, float* __restrict__ Out)
{
  const int idx = blockIdx.x * 256 + threadIdx.x;
  const int q = idx >> 7;
  const int d4 = idx & 127;
  const char* p = obase + (size_t)q * qstride + (size_t)d4 * 16;
  f32x4 s = *(const f32x4*)p;
  for (int zz = 1; zz < Z; ++zz)
    s += *(const f32x4*)(p + (size_t)zz * zstride);
  float linv = 1.0f / Lsum[q];
  s *= linv;
  *(f32x4*)(Out + (size_t)q * DIM + d4 * 4) = s;
}

// ---------------------------------------------------------------------------
extern "C" void kernel_launch(void* const* d_in, const int* in_sizes, int n_in,
                              void* d_out, int out_size, void* d_ws, size_t ws_size,
                              hipStream_t stream) {
  const float* Wq = (const float*)d_in[0];
  const float* Wk = (const float*)d_in[1];
  const float* X  = (const float*)d_in[2];
  float* Out = (float*)d_out;

  char* w = (char*)d_ws;
  const size_t SPLIT  = (size_t)NSEQ * DIM * 2;          // 8 MB
  const size_t XBYTES = (size_t)DIM * VPITCH * 2;        // 8.45 MB (row XhT)
  const size_t WTB    = (size_t)DIM * DIM * 2;
  f16* Qh  = (f16*)(w);
  f16* Ql  = (f16*)(w + SPLIT);
  f16* Kh  = (f16*)(w + 2 * SPLIT);
  f16* Kl  = (f16*)(w + 3 * SPLIT);
  f16* XhT = (f16*)(w + 4 * SPLIT);                      // frag OR row layout
  f16* Xh  = (f16*)(w + 4 * SPLIT + XBYTES);
  f16* Xl  = (f16*)(w + 5 * SPLIT + XBYTES);
  f16* Wth = (f16*)(w + 6 * SPLIT + XBYTES);
  f16* Wtl = (f16*)(w + 6 * SPLIT + XBYTES + WTB);
  float* Lsum = (float*)(w + 6 * SPLIT + XBYTES + 2 * WTB);
  const size_t used_base = 6 * SPLIT + XBYTES + 2 * WTB + 32768;
  char* rest = w + used_base;
  const size_t PFB    = (size_t)NSEQ * NSEQ * 2;         // 128 MB frag P
  const size_t PBYTES = (size_t)NSEQ * SPITCH * 2;       // 135 MB row P
  const size_t OPART1 = (size_t)NSEQ * DIM * 4;          // 16 MB per partial

  const float SCALE = 0.044194173824159216f;  // 1/sqrt(512)
  const bool good = ws_size >= used_base + PFB + (size_t)128 * SROWB;

  // common pre-passes
  k_splitx<<<NSEQ * DIM / (256 * 4), 256, 0, stream>>>(X, Xh, Xl);
  if (good) k_xt2<<<dim3(NSEQ / 64, DIM / 64), 256, 0, stream>>>(X, XhT);
  else      k_xt <<<dim3(NSEQ / 64, DIM / 64), 256, 0, stream>>>(X, XhT);
  k_splitwt<<<dim3(8, 8), 256, 0, stream>>>(Wq, Wth, Wtl);
  k_proj2<<<dim3(NSEQ / 128, DIM / 128), 256, 0, stream>>>(Xh, Xl, Wth, Wtl, Qh, Ql, SCALE);
  k_splitwt<<<dim3(8, 8), 256, 0, stream>>>(Wk, Wth, Wtl);
  k_proj2<<<dim3(NSEQ / 128, DIM / 128), 256, 0, stream>>>(Xh, Xl, Wth, Wtl, Kh, Kl, 1.0f);

  if (good) {
    f16* Pf = (f16*)rest;
    float* S = (float*)(rest + PFB);
    size_t avail = ws_size - used_base - PFB;
    int CQ = 2048;
    while (CQ > 128 && (size_t)CQ * SROWB > avail) CQ >>= 1;
    size_t schunk = (size_t)CQ * SROWB;
    int zc = (int)(schunk / OPART1);
    int Z = (zc >= 4) ? 4 : (zc >= 2) ? 2 : 1;
    char* obase; size_t qstride = DIM * 4, zstride;
    if (Z >= 2) { obase = (char*)S; zstride = OPART1; }
    else { Z = 1; obase = (char*)Out; zstride = 0; }

    for (int q0 = 0; q0 < NSEQ; q0 += CQ) {
      k_qkt2<<<dim3(CQ / 128, NSEQ / 128), 256, 0, stream>>>(Qh, Ql, Kh, Kl, S, q0);
      k_softmax2<<<dim3(CQ), 256, 0, stream>>>(S, Pf, Lsum, q0);
    }
    k_pv2f<<<dim3(256 * Z), 256, 0, stream>>>(XhT, Pf, obase, qstride, zstride,
                                              NSEQ / Z, Z);
    k_reduce<<<NSEQ * (DIM / 4) / 256, 256, 0, stream>>>(obase, qstride, zstride,
                                                         Z, Lsum, Out);
  } else {
    f16* P = (f16*)rest;
    float* S = (float*)(rest + PBYTES);
    size_t avail = (ws_size > used_base + PBYTES) ? ws_size - used_base - PBYTES : 0;
    int CQ = 2048;
    while (CQ > 128 && (size_t)CQ * SROWB > avail) CQ >>= 1;
    size_t schunk = (size_t)CQ * SROWB;
    int zc = (int)(schunk / OPART1);
    int Z = (zc >= 4) ? 4 : (zc >= 2) ? 2 : 1;
    char* obase; size_t qstride = DIM * 4, zstride;
    if (Z >= 2) { obase = (char*)S; zstride = OPART1; }
    else { Z = 1; obase = (char*)Out; zstride = 0; }

    for (int q0 = 0; q0 < NSEQ; q0 += CQ) {
      k_qkt2<<<dim3(CQ / 128, NSEQ / 128), 256, 0, stream>>>(Qh, Ql, Kh, Kl, S, q0);
      k_softmax_row<<<dim3(CQ), 256, 0, stream>>>(S, P, Lsum, q0);
    }
    k_pv2_row<<<dim3(256 * Z), 256, 0, stream>>>(XhT, P, obase, qstride, zstride,
                                                 NSEQ / Z, Z);
    k_reduce<<<NSEQ * (DIM / 4) / 256, 256, 0, stream>>>(obase, qstride, zstride,
                                                         Z, Lsum, Out);
  }
}